// Round 9
// baseline (247.187 us; speedup 1.0000x reference)
//
#include <hip/hip_runtime.h>

// LinearRNN as truncated FIR convolution:
//   y_t = sum_{i=0}^{32} G_i u_{t-i} + C A^t x0,   G_0 = D, G_i = C A^{i-1} B.
// R11 (v8): phase diversity via small blocks.
//   R8 post-mortem: unified VGPR/AGPR file -> wave footprint 152-176 regs ->
//   3 waves/SIMD max -> an 8-wave block (needs 2/SIMD x2 blocks = 4/SIMD)
//   can never double-up: 1 block/CU, all 8 waves lockstep, phases serialize
//   (MFMA 34 + LDS 24 + stage 12 + VALU 13 ~= 83us ~= wall). Intra-wave ILP
//   fixes (R3/R5/R8) all null because the problem is CU-level phase overlap.
//   Fix: 4-wave/256-thr/256-row blocks, LDS 36,864 B, no fence (VGPR back to
//   88 -> 152 total -> 3 waves/SIMD) -> 3 INDEPENDENT blocks/CU at staggered
//   phases; staging of one overlaps MFMA of another. Wave tile unchanged
//   (128x32, 1056 MFMA, G-dbuf, XOR swizzle 0-conflict, batched reads).

#define T_LEN  262144
#define NTAP   33      // taps 0..32
#define ZLEN   48      // x0-correction horizon
#define ROWS   256     // output rows per conv block (4 waves x 128x32)
#define HALO   32

typedef __attribute__((ext_vector_type(8))) short  short8;
typedef __attribute__((ext_vector_type(4))) short  short4v;
typedef __attribute__((ext_vector_type(4))) float  floatx4;

static __device__ __forceinline__ unsigned short f2bf(float f) {
    unsigned int x = __float_as_uint(f);
    x += 0x7fffu + ((x >> 16) & 1u);     // RNE (finite normals)
    return (unsigned short)(x >> 16);
}
static __device__ __forceinline__ float bf2f(unsigned short u) {
    return __uint_as_float(((unsigned int)u) << 16);
}

// ---------------------------------------------------------------------------
// K1: log-depth prep, UNCHANGED from R2..R8 (passed, absmax 0.094).
// pool slots: 0:An 1:At 2:Bt 3:E2n 4:E2t 5:E4t 6..9: M0..M3 (chain ping)
// ---------------------------------------------------------------------------
__global__ __launch_bounds__(256, 1) void k_prep(
    const float* __restrict__ A, const float* __restrict__ B,
    const float* __restrict__ C, const float* __restrict__ D,
    const float* __restrict__ x0, unsigned short* __restrict__ gG,
    float* __restrict__ gZ)
{
    __shared__ unsigned short pool[10][64][72];   // 92,160 B
    const int tid = threadIdx.x;
    const int wv = tid >> 6, lane = tid & 63, l15 = lane & 15, q = lane >> 4;

#pragma unroll
    for (int e = 0; e < 16; ++e) {
        int f = e * 256 + tid;
        int r = f >> 6, c = f & 63;
        unsigned short av = f2bf(A[f]);
        pool[0][r][c] = av;                // An
        pool[1][c][r] = av;                // At
        pool[2][c][r] = f2bf(B[f]);        // Bt
        pool[6][r][c] = f2bf(C[f]);        // M0 = C
        gG[f]         = f2bf(D[f]);        // G_0 = D
    }
    __syncthreads();

    float x0v[4];
#pragma unroll
    for (int nt = 0; nt < 4; ++nt) x0v[nt] = x0[l15 + 16 * nt];

    // phase 2: A2 = A*A, M1 = C*A
    {
        short8 bA[2][4];
#pragma unroll
        for (int kb = 0; kb < 2; ++kb)
#pragma unroll
            for (int nt = 0; nt < 4; ++nt)
                bA[kb][nt] = *(const short8*)&pool[1][l15 + 16*nt][kb*32 + q*8];

        short8 a0 = *(const short8*)&pool[0][16*wv + l15][q*8];
        short8 a1 = *(const short8*)&pool[0][16*wv + l15][32 + q*8];
#pragma unroll
        for (int nt = 0; nt < 4; ++nt) {
            floatx4 m = (floatx4){0.f, 0.f, 0.f, 0.f};
            m = __builtin_amdgcn_mfma_f32_16x16x32_bf16(a0, bA[0][nt], m, 0, 0, 0);
            m = __builtin_amdgcn_mfma_f32_16x16x32_bf16(a1, bA[1][nt], m, 0, 0, 0);
#pragma unroll
            for (int r = 0; r < 4; ++r) {
                unsigned short h = f2bf(m[r]);
                pool[3][16*wv + q*4 + r][l15 + 16*nt] = h;   // E2n
                pool[4][l15 + 16*nt][16*wv + q*4 + r] = h;   // E2t
            }
        }
        a0 = *(const short8*)&pool[6][16*wv + l15][q*8];
        a1 = *(const short8*)&pool[6][16*wv + l15][32 + q*8];
#pragma unroll
        for (int nt = 0; nt < 4; ++nt) {
            floatx4 m = (floatx4){0.f, 0.f, 0.f, 0.f};
            m = __builtin_amdgcn_mfma_f32_16x16x32_bf16(a0, bA[0][nt], m, 0, 0, 0);
            m = __builtin_amdgcn_mfma_f32_16x16x32_bf16(a1, bA[1][nt], m, 0, 0, 0);
#pragma unroll
            for (int r = 0; r < 4; ++r)
                pool[7][16*wv + q*4 + r][l15 + 16*nt] = f2bf(m[r]);   // M1
        }
    }
    __syncthreads();

    // phase 3: E4t = (A2*A2)^T slice; M2 = C*A2; M3 = M1*A2
    {
        short8 bA2[2][4];
#pragma unroll
        for (int kb = 0; kb < 2; ++kb)
#pragma unroll
            for (int nt = 0; nt < 4; ++nt)
                bA2[kb][nt] = *(const short8*)&pool[4][l15 + 16*nt][kb*32 + q*8];

        short8 a0 = *(const short8*)&pool[3][16*wv + l15][q*8];
        short8 a1 = *(const short8*)&pool[3][16*wv + l15][32 + q*8];
#pragma unroll
        for (int nt = 0; nt < 4; ++nt) {
            floatx4 m = (floatx4){0.f, 0.f, 0.f, 0.f};
            m = __builtin_amdgcn_mfma_f32_16x16x32_bf16(a0, bA2[0][nt], m, 0, 0, 0);
            m = __builtin_amdgcn_mfma_f32_16x16x32_bf16(a1, bA2[1][nt], m, 0, 0, 0);
#pragma unroll
            for (int r = 0; r < 4; ++r)
                pool[5][l15 + 16*nt][16*wv + q*4 + r] = f2bf(m[r]);   // E4t
        }
        a0 = *(const short8*)&pool[6][16*wv + l15][q*8];
        a1 = *(const short8*)&pool[6][16*wv + l15][32 + q*8];
#pragma unroll
        for (int nt = 0; nt < 4; ++nt) {
            floatx4 m = (floatx4){0.f, 0.f, 0.f, 0.f};
            m = __builtin_amdgcn_mfma_f32_16x16x32_bf16(a0, bA2[0][nt], m, 0, 0, 0);
            m = __builtin_amdgcn_mfma_f32_16x16x32_bf16(a1, bA2[1][nt], m, 0, 0, 0);
#pragma unroll
            for (int r = 0; r < 4; ++r)
                pool[8][16*wv + q*4 + r][l15 + 16*nt] = f2bf(m[r]);   // M2
        }
        a0 = *(const short8*)&pool[7][16*wv + l15][q*8];
        a1 = *(const short8*)&pool[7][16*wv + l15][32 + q*8];
#pragma unroll
        for (int nt = 0; nt < 4; ++nt) {
            floatx4 m = (floatx4){0.f, 0.f, 0.f, 0.f};
            m = __builtin_amdgcn_mfma_f32_16x16x32_bf16(a0, bA2[0][nt], m, 0, 0, 0);
            m = __builtin_amdgcn_mfma_f32_16x16x32_bf16(a1, bA2[1][nt], m, 0, 0, 0);
#pragma unroll
            for (int r = 0; r < 4; ++r)
                pool[9][16*wv + q*4 + r][l15 + 16*nt] = f2bf(m[r]);   // M3
        }
    }
    __syncthreads();

    short8 bE[2][4], bB[2][4];
#pragma unroll
    for (int kb = 0; kb < 2; ++kb)
#pragma unroll
        for (int nt = 0; nt < 4; ++nt) {
            bE[kb][nt] = *(const short8*)&pool[5][l15 + 16*nt][kb*32 + q*8];
            bB[kb][nt] = *(const short8*)&pool[2][l15 + 16*nt][kb*32 + q*8];
        }
    __syncthreads();   // pool[0..4] now reusable as chain pong buffers

    unsigned short (*cur)[72] = pool[6 + wv];
    unsigned short (*alt)[72] = pool[wv];

#pragma unroll
    for (int mt = 0; mt < 4; ++mt)
#pragma unroll
        for (int r = 0; r < 4; ++r) {
            float v = 0.f;
#pragma unroll
            for (int nt = 0; nt < 4; ++nt)
                v += bf2f(cur[16*mt + q*4 + r][l15 + 16*nt]) * x0v[nt];
            v += __shfl_xor(v, 1, 16); v += __shfl_xor(v, 2, 16);
            v += __shfl_xor(v, 4, 16); v += __shfl_xor(v, 8, 16);
            if (l15 == 0) gZ[wv*64 + 16*mt + q*4 + r] = v;
        }

    for (int k = 1; k <= 11; ++k) {
        const int jm = 4*(k-1) + wv;     // cur = M_jm
        short8 a0[4], a1[4];
#pragma unroll
        for (int mt = 0; mt < 4; ++mt) {
            a0[mt] = *(const short8*)&cur[16*mt + l15][q*8];
            a1[mt] = *(const short8*)&cur[16*mt + l15][32 + q*8];
        }
        if (jm < 32) {                   // G_{jm+1} = M_jm * B
#pragma unroll
            for (int mt = 0; mt < 4; ++mt)
#pragma unroll
                for (int nt = 0; nt < 4; ++nt) {
                    floatx4 g = (floatx4){0.f, 0.f, 0.f, 0.f};
                    g = __builtin_amdgcn_mfma_f32_16x16x32_bf16(a0[mt], bB[0][nt], g, 0, 0, 0);
                    g = __builtin_amdgcn_mfma_f32_16x16x32_bf16(a1[mt], bB[1][nt], g, 0, 0, 0);
#pragma unroll
                    for (int r = 0; r < 4; ++r)
                        gG[(size_t)(jm+1)*4096 + (16*mt + q*4 + r)*64 + l15 + 16*nt] = f2bf(g[r]);
                }
        }
        floatx4 m[4][4];
#pragma unroll
        for (int mt = 0; mt < 4; ++mt)
#pragma unroll
            for (int nt = 0; nt < 4; ++nt) {
                m[mt][nt] = (floatx4){0.f, 0.f, 0.f, 0.f};
                m[mt][nt] = __builtin_amdgcn_mfma_f32_16x16x32_bf16(a0[mt], bE[0][nt], m[mt][nt], 0, 0, 0);
                m[mt][nt] = __builtin_amdgcn_mfma_f32_16x16x32_bf16(a1[mt], bE[1][nt], m[mt][nt], 0, 0, 0);
            }
#pragma unroll
        for (int mt = 0; mt < 4; ++mt)
#pragma unroll
            for (int nt = 0; nt < 4; ++nt)
#pragma unroll
                for (int r = 0; r < 4; ++r)
                    alt[16*mt + q*4 + r][l15 + 16*nt] = f2bf(m[mt][nt][r]);
        const int zi = 4*k + wv;
#pragma unroll
        for (int mt = 0; mt < 4; ++mt)
#pragma unroll
            for (int r = 0; r < 4; ++r) {
                float v = 0.f;
#pragma unroll
                for (int nt = 0; nt < 4; ++nt) v = fmaf(m[mt][nt][r], x0v[nt], v);
                v += __shfl_xor(v, 1, 16); v += __shfl_xor(v, 2, 16);
                v += __shfl_xor(v, 4, 16); v += __shfl_xor(v, 8, 16);
                if (l15 == 0) gZ[zi*64 + 16*mt + q*4 + r] = v;
            }
        unsigned short (*tmp)[72] = cur; cur = alt; alt = tmp;
    }
}

// ---------------------------------------------------------------------------
// K2 v8: 4-wave blocks for cross-block phase overlap.
// 256 thr = 4 waves; rg=w>>1 owns 128 rows (8 mt), nhalf=w&1 owns 32 cols.
// Wave tile / G-dbuf / tap pairing / swizzle / batched reads: as R6.
// LDS 36,864 B; target residency 3 blocks/CU (152 regs/wave -> 3 waves/SIMD).
// ---------------------------------------------------------------------------
__global__ __launch_bounds__(256, 3) void k_conv(
    const float* __restrict__ u, const unsigned short* __restrict__ gG,
    const float* __restrict__ gZ, float* __restrict__ out)
{
    __shared__ __align__(16) unsigned char uS[(ROWS + HALO) * 128];  // 36,864 B
    const int tid = threadIdx.x;
    const int wv = tid >> 6, lane = tid & 63, l15 = lane & 15, q = lane >> 4;
    const int nhalf = wv & 1, rg = wv >> 1;
    const int t0 = blockIdx.x * ROWS;

    // stage u rows [t0-32, t0+256) as bf16 (rows < 0 -> zeros, block 0 only)
    {
        const float4* u4 = (const float4*)u;
        const int base4 = (t0 - HALO) * 16;     // float4 index of first staged row
#pragma unroll
        for (int e = 0; e < 18; ++e) {
            int f = e * 256 + tid;              // 4608 float4 total
            float4 v = make_float4(0.f, 0.f, 0.f, 0.f);
            if (base4 + f >= 0) v = u4[base4 + f];
            int r  = f >> 4;                    // LDS row
            int cb = (f & 15) * 8;              // col byte (8 B granule, bit3 safe)
            short4v pk;
            pk[0] = (short)f2bf(v.x); pk[1] = (short)f2bf(v.y);
            pk[2] = (short)f2bf(v.z); pk[3] = (short)f2bf(v.w);
            *(short4v*)(uS + (r * 128 + (cb ^ ((r & 7) << 4)))) = pk;
        }
    }
    __syncthreads();

    floatx4 acc[8][2];
#pragma unroll
    for (int mt = 0; mt < 8; ++mt)
#pragma unroll
        for (int nt = 0; nt < 2; ++nt) acc[mt][nt] = (floatx4){0.f, 0.f, 0.f, 0.f};

    // b-frag loader for tap pair {j, j+16}
    auto loadG2 = [&](short8 (&c0)[2][2], short8 (&c1)[2][2], int j) {
#pragma unroll
        for (int kb = 0; kb < 2; ++kb)
#pragma unroll
            for (int nt = 0; nt < 2; ++nt) {
                const size_t off = (size_t)(l15 + 16*(2*nhalf + nt))*64 + kb*32 + q*8;
                c1[kb][nt] = *(const short8*)(gG + (size_t)(j + 16)*4096 + off);
                c0[kb][nt] = *(const short8*)(gG + (size_t)j*4096 + off);
            }
    };
    // rt sweep for tap pair {j, j+16}: read rt feeds tap j at mt=rt-1 and
    // tap j+16 at mt=rt.  LDS row = rg*128 + 16*rt + 16 - j + l15.
    auto sweep = [&](const short8 (&c0)[2][2], const short8 (&c1)[2][2], int j) {
        const int swz  = ((l15 - j) & 7) << 4;
        const int rowb = (rg*128 + 16 - j + l15) * 128;
        const int cb0 = (q * 16) ^ swz;
        const int cb1 = (64 + q * 16) ^ swz;
        short8 av[9], bv[9];
#pragma unroll
        for (int rt = 0; rt <= 8; ++rt)
            av[rt] = *(const short8*)(uS + (rowb + rt * 2048 + cb0));
#pragma unroll
        for (int rt = 0; rt <= 8; ++rt)
            bv[rt] = *(const short8*)(uS + (rowb + rt * 2048 + cb1));
#pragma unroll
        for (int rt = 0; rt <= 8; ++rt) {
            if (rt >= 1) {                  // tap j,   mt = rt-1
#pragma unroll
                for (int nt = 0; nt < 2; ++nt)
                    acc[rt-1][nt] = __builtin_amdgcn_mfma_f32_16x16x32_bf16(
                        av[rt], c0[0][nt], acc[rt-1][nt], 0, 0, 0);
            }
            if (rt <= 7) {                  // tap j+16, mt = rt
#pragma unroll
                for (int nt = 0; nt < 2; ++nt)
                    acc[rt][nt] = __builtin_amdgcn_mfma_f32_16x16x32_bf16(
                        av[rt], c1[0][nt], acc[rt][nt], 0, 0, 0);
            }
        }
#pragma unroll
        for (int rt = 0; rt <= 8; ++rt) {
            if (rt >= 1) {
#pragma unroll
                for (int nt = 0; nt < 2; ++nt)
                    acc[rt-1][nt] = __builtin_amdgcn_mfma_f32_16x16x32_bf16(
                        bv[rt], c0[1][nt], acc[rt-1][nt], 0, 0, 0);
            }
            if (rt <= 7) {
#pragma unroll
                for (int nt = 0; nt < 2; ++nt)
                    acc[rt][nt] = __builtin_amdgcn_mfma_f32_16x16x32_bf16(
                        bv[rt], c1[1][nt], acc[rt][nt], 0, 0, 0);
            }
        }
    };

    // software-pipelined main loop: two static G buffer sets, unroll-2 over j
    short8 bA0[2][2], bA1[2][2], bB0[2][2], bB1[2][2];
    loadG2(bA0, bA1, 0);
#pragma unroll 1
    for (int jj = 0; jj < 8; ++jj) {
        loadG2(bB0, bB1, 2*jj + 1);         // prefetch j+1 (hidden under sweep j)
        sweep(bA0, bA1, 2*jj);
        if (jj < 7) loadG2(bA0, bA1, 2*jj + 2);  // prefetch j+2
        sweep(bB0, bB1, 2*jj + 1);
    }

    // tail: tap 32 (LDS row = rg*128 + 16mt + l15)
    {
        short8 bt[2][2];
#pragma unroll
        for (int kb = 0; kb < 2; ++kb)
#pragma unroll
            for (int nt = 0; nt < 2; ++nt)
                bt[kb][nt] = *(const short8*)(gG + (size_t)32*4096
                                  + (size_t)(l15 + 16*(2*nhalf + nt))*64 + kb*32 + q*8);
        const int swz  = (l15 & 7) << 4;
        const int rowb = (rg*128 + l15) * 128;
        const int cb0 = (q * 16) ^ swz;
        const int cb1 = (64 + q * 16) ^ swz;
        short8 av[8], bv[8];
#pragma unroll
        for (int mt = 0; mt < 8; ++mt)
            av[mt] = *(const short8*)(uS + (rowb + mt * 2048 + cb0));
#pragma unroll
        for (int mt = 0; mt < 8; ++mt)
            bv[mt] = *(const short8*)(uS + (rowb + mt * 2048 + cb1));
#pragma unroll
        for (int mt = 0; mt < 8; ++mt)
#pragma unroll
            for (int nt = 0; nt < 2; ++nt)
                acc[mt][nt] = __builtin_amdgcn_mfma_f32_16x16x32_bf16(
                    av[mt], bt[0][nt], acc[mt][nt], 0, 0, 0);
#pragma unroll
        for (int mt = 0; mt < 8; ++mt)
#pragma unroll
            for (int nt = 0; nt < 2; ++nt)
                acc[mt][nt] = __builtin_amdgcn_mfma_f32_16x16x32_bf16(
                    bv[mt], bt[1][nt], acc[mt][nt], 0, 0, 0);
    }

    // epilogue: row = rg*128 + 16mt + q*4 + r, col = 32*nhalf + 16nt + l15
    const bool zblk = (blockIdx.x == 0 && rg == 0);
#pragma unroll
    for (int mt = 0; mt < 8; ++mt)
#pragma unroll
        for (int nt = 0; nt < 2; ++nt) {
            const int p = l15 + 32*nhalf + 16*nt;
#pragma unroll
            for (int r = 0; r < 4; ++r) {
                int tl = rg*128 + mt*16 + q*4 + r;
                float v = acc[mt][nt][r];
                if (zblk && mt < 3) v += gZ[(mt*16 + q*4 + r)*64 + p];  // t < 48
                out[(size_t)(t0 + tl)*64 + p] = v;
            }
        }
}

extern "C" void kernel_launch(void* const* d_in, const int* in_sizes, int n_in,
                              void* d_out, int out_size, void* d_ws, size_t ws_size,
                              hipStream_t stream) {
    const float* u  = (const float*)d_in[0];
    const float* x0 = (const float*)d_in[1];
    const float* A  = (const float*)d_in[2];
    const float* B  = (const float*)d_in[3];
    const float* C  = (const float*)d_in[4];
    const float* D  = (const float*)d_in[5];
    float* out = (float*)d_out;

    unsigned short* gG = (unsigned short*)d_ws;                  // 33*4096 bf16 = 270 KB
    float* gZ = (float*)((char*)d_ws + 272384);                  // 48*64 fp32

    hipLaunchKernelGGL(k_prep, dim3(1), dim3(256), 0, stream,
                       A, B, C, D, x0, gG, gZ);
    hipLaunchKernelGGL(k_conv, dim3(T_LEN / ROWS), dim3(256), 0, stream,
                       u, gG, gZ, out);
}

// Round 10
// 212.044 us; speedup vs baseline: 1.1657x; 1.1657x over previous
//
#include <hip/hip_runtime.h>

// LinearRNN as truncated FIR convolution:
//   y_t = sum_{i=0}^{32} G_i u_{t-i} + C A^t x0,   G_0 = D, G_i = C A^{i-1} B.
// R12 (v9): two independent changes, separately attributable:
//  1) k_prep -> k_prep_pow: 48 parallel blocks; block t builds A^t by binary
//     powering (<=5 squares + <=5 R-mults, fp32-acc bf16 matmuls), emits
//     G_{t+1} = (C A^t) B for t<32, z_t = (C A^t) x0 for t<48. Serial depth
//     ~6 on 48 CUs vs ~13 on 1 CU -> ~3us. DIAGNOSTIC for the constant
//     ~135us residual (total - k_conv) seen in ALL rounds.
//  2) k_conv staging -> k_cast (R7-verified fp32->bf16 + 32 zero halo rows)
//     + global_load_lds width=16 with pre-swizzled per-lane SOURCE and
//     linear LDS dest (rule #21; read-side XOR swizzle unchanged, verified
//     0 conflicts). Removes all staging VALU (f2bf packs, 12% VALUBusy) and
//     the reg round-trip (guide Common-mistake #1). Sweep/G-dbuf/tap-pairing
//     byte-identical to R9.

#define T_LEN  262144
#define NTAP   33      // taps 0..32
#define ZLEN   48      // x0-correction horizon
#define ROWS   256     // output rows per conv block (4 waves x 128x32)
#define HALO   32
#define UB_ROWS (T_LEN + HALO)

typedef __attribute__((ext_vector_type(8))) short  short8;
typedef __attribute__((ext_vector_type(4))) float  floatx4;
typedef __attribute__((address_space(1))) const void gas_void;
typedef __attribute__((address_space(3))) void las_void;

static __device__ __forceinline__ unsigned short f2bf(float f) {
    unsigned int x = __float_as_uint(f);
    x += 0x7fffu + ((x >> 16) & 1u);     // RNE (finite normals)
    return (unsigned short)(x >> 16);
}
static __device__ __forceinline__ float bf2f(unsigned short u) {
    return __uint_as_float(((unsigned int)u) << 16);
}

// ---------------------------------------------------------------------------
// K0: u (fp32, T x 64) -> uB (bf16, [32 zero rows][T rows] x 64).
// R7-verified. 8193 blocks x 256 thr, exact cover.
// ---------------------------------------------------------------------------
__global__ __launch_bounds__(256) void k_cast(
    const float* __restrict__ u, unsigned short* __restrict__ uB)
{
    const size_t e8 = ((size_t)blockIdx.x * 256 + threadIdx.x) * 8;
    short8 pk;
    if (e8 < (size_t)HALO * 64) {
        pk = (short8){0, 0, 0, 0, 0, 0, 0, 0};
    } else {
        const float4* s = (const float4*)(u + (e8 - (size_t)HALO * 64));
        float4 v0 = s[0], v1 = s[1];
        pk[0] = (short)f2bf(v0.x); pk[1] = (short)f2bf(v0.y);
        pk[2] = (short)f2bf(v0.z); pk[3] = (short)f2bf(v0.w);
        pk[4] = (short)f2bf(v1.x); pk[5] = (short)f2bf(v1.y);
        pk[6] = (short)f2bf(v1.z); pk[7] = (short)f2bf(v1.w);
    }
    *(short8*)(uB + e8) = pk;
}

// ---------------------------------------------------------------------------
// K1 v2: parallel prep. Grid = 48 blocks (one per t), 256 thr = 4 waves.
// Block t: S=A, R=C; for bit k of t: R=R*S (if set), S=S*S (if higher bits);
// then z_t = R x0; if t<32: G_{t+1} = R*B. Block 0 also copies G_0 = D.
// Each matmul: wave w owns rows 16w..16w+15; right operand read transposed.
// ---------------------------------------------------------------------------
__global__ __launch_bounds__(256, 1) void k_prep_pow(
    const float* __restrict__ A, const float* __restrict__ B,
    const float* __restrict__ C, const float* __restrict__ D,
    const float* __restrict__ x0, unsigned short* __restrict__ gG,
    float* __restrict__ gZ)
{
    __shared__ unsigned short Sn0[64][72], Sn1[64][72];   // S natural (ping/pong)
    __shared__ unsigned short St0[64][72], St1[64][72];   // S transposed
    __shared__ unsigned short Rn0[64][72], Rn1[64][72];   // R natural
    __shared__ unsigned short Bt [64][72];                // B transposed
    const int t   = blockIdx.x;
    const int tid = threadIdx.x;
    const int wv = tid >> 6, lane = tid & 63, l15 = lane & 15, q = lane >> 4;

    // stage: S0 = A (both layouts), R0 = C, Bt = B^T; block 0 copies D -> G_0
#pragma unroll
    for (int e = 0; e < 16; ++e) {
        int f = e * 256 + tid;
        int r = f >> 6, c = f & 63;
        unsigned short av = f2bf(A[f]);
        Sn0[r][c] = av;
        St0[c][r] = av;
        Rn0[r][c] = f2bf(C[f]);
        Bt [c][r] = f2bf(B[f]);
        if (t == 0) gG[f] = f2bf(D[f]);
    }
    __syncthreads();

    // matmul: dst = srcN * (srcT)^T-stored-right; optionally also write dst^T
    auto mm = [&](unsigned short (*dN)[72], unsigned short (*dT)[72],
                  unsigned short (*sN)[72], unsigned short (*sT)[72]) {
        short8 a0 = *(const short8*)&sN[16*wv + l15][q*8];
        short8 a1 = *(const short8*)&sN[16*wv + l15][32 + q*8];
#pragma unroll
        for (int nt = 0; nt < 4; ++nt) {
            short8 b0 = *(const short8*)&sT[l15 + 16*nt][q*8];
            short8 b1 = *(const short8*)&sT[l15 + 16*nt][32 + q*8];
            floatx4 m = (floatx4){0.f, 0.f, 0.f, 0.f};
            m = __builtin_amdgcn_mfma_f32_16x16x32_bf16(a0, b0, m, 0, 0, 0);
            m = __builtin_amdgcn_mfma_f32_16x16x32_bf16(a1, b1, m, 0, 0, 0);
#pragma unroll
            for (int r = 0; r < 4; ++r) {
                unsigned short h = f2bf(m[r]);
                dN[16*wv + q*4 + r][l15 + 16*nt] = h;
                if (dT) dT[l15 + 16*nt][16*wv + q*4 + r] = h;
            }
        }
    };

    unsigned short (*SnC)[72] = Sn0, (*SnA)[72] = Sn1;
    unsigned short (*StC)[72] = St0, (*StA)[72] = St1;
    unsigned short (*RnC)[72] = Rn0, (*RnA)[72] = Rn1;

    for (int k = 0; k < 6; ++k) {
        const bool mulR = (t >> k) & 1;
        const bool more = (t >> (k + 1)) != 0;
        if (mulR) mm(RnA, (unsigned short (*)[72])nullptr, RnC, StC);
        if (more) mm(SnA, StA, SnC, StC);
        if (!mulR && !more) break;        // t == 0, or exhausted (defensive)
        __syncthreads();
        if (mulR) { auto tp = RnC; RnC = RnA; RnA = tp; }
        if (more) { auto tp = SnC; SnC = SnA; SnA = tp;
                    tp = StC; StC = StA; StA = tp; }
        if (!more) break;
    }
    // R = C * A^t  (bf16 in RnC). Last loop iteration ended with a barrier.

    // z_t = R x0  (16 rows per wave)
    float x0v[4];
#pragma unroll
    for (int nt = 0; nt < 4; ++nt) x0v[nt] = x0[l15 + 16 * nt];
#pragma unroll
    for (int r = 0; r < 4; ++r) {
        float v = 0.f;
#pragma unroll
        for (int nt = 0; nt < 4; ++nt)
            v += bf2f(RnC[16*wv + q*4 + r][l15 + 16*nt]) * x0v[nt];
        v += __shfl_xor(v, 1, 16); v += __shfl_xor(v, 2, 16);
        v += __shfl_xor(v, 4, 16); v += __shfl_xor(v, 8, 16);
        if (l15 == 0) gZ[t*64 + 16*wv + q*4 + r] = v;
    }

    // G_{t+1} = R * B  (t < 32)
    if (t < 32) {
        short8 a0 = *(const short8*)&RnC[16*wv + l15][q*8];
        short8 a1 = *(const short8*)&RnC[16*wv + l15][32 + q*8];
#pragma unroll
        for (int nt = 0; nt < 4; ++nt) {
            short8 b0 = *(const short8*)&Bt[l15 + 16*nt][q*8];
            short8 b1 = *(const short8*)&Bt[l15 + 16*nt][32 + q*8];
            floatx4 g = (floatx4){0.f, 0.f, 0.f, 0.f};
            g = __builtin_amdgcn_mfma_f32_16x16x32_bf16(a0, b0, g, 0, 0, 0);
            g = __builtin_amdgcn_mfma_f32_16x16x32_bf16(a1, b1, g, 0, 0, 0);
#pragma unroll
            for (int r = 0; r < 4; ++r)
                gG[(size_t)(t+1)*4096 + (16*wv + q*4 + r)*64 + l15 + 16*nt] = f2bf(g[r]);
        }
    }
}

// ---------------------------------------------------------------------------
// K2 v9: R9's conv body with global_load_lds staging from uB.
// 256 thr = 4 waves; rg=w>>1 owns 128 rows (8 mt), nhalf=w&1 owns 32 cols.
// Staging: wave w DMAs 72 rows (9 insts x 1KB) with per-lane PRE-SWIZZLED
// global source and LINEAR LDS dest (rule #21); reads keep the XOR swizzle
// (verified 0 conflicts). No staging VALU, no bounds check (uB zero halo).
// ---------------------------------------------------------------------------
__global__ __launch_bounds__(256, 3) void k_conv(
    const unsigned short* __restrict__ uB, const unsigned short* __restrict__ gG,
    const float* __restrict__ gZ, float* __restrict__ out)
{
    __shared__ __align__(16) unsigned char uS[(ROWS + HALO) * 128];  // 36,864 B
    const int tid = threadIdx.x;
    const int wv = tid >> 6, lane = tid & 63, l15 = lane & 15, q = lane >> 4;
    const int nhalf = wv & 1, rg = wv >> 1;
    const int t0 = blockIdx.x * ROWS;

    // stage local rows [0,288) = u rows [t0-32, t0+256) via direct-to-LDS DMA
    {
        const int r0 = wv * 72;               // wave's first local row
        const int lr = lane >> 3;             // row-within-8 for this lane
        const int pb = (lane & 7) * 16;       // physical byte within row
        const unsigned char* uBb = (const unsigned char*)uB;
#pragma unroll
        for (int i = 0; i < 9; ++i) {
            const int r = r0 + i * 8 + lr;    // local row this lane covers
            const size_t gb = (((size_t)(t0 + r)) << 7) + (pb ^ ((r & 7) << 4));
            __builtin_amdgcn_global_load_lds(
                (gas_void*)(uBb + gb),
                (las_void*)(uS + (size_t)(r0 + i * 8) * 128),
                16, 0, 0);
        }
    }
    __syncthreads();

    floatx4 acc[8][2];
#pragma unroll
    for (int mt = 0; mt < 8; ++mt)
#pragma unroll
        for (int nt = 0; nt < 2; ++nt) acc[mt][nt] = (floatx4){0.f, 0.f, 0.f, 0.f};

    // b-frag loader for tap pair {j, j+16}
    auto loadG2 = [&](short8 (&c0)[2][2], short8 (&c1)[2][2], int j) {
#pragma unroll
        for (int kb = 0; kb < 2; ++kb)
#pragma unroll
            for (int nt = 0; nt < 2; ++nt) {
                const size_t off = (size_t)(l15 + 16*(2*nhalf + nt))*64 + kb*32 + q*8;
                c1[kb][nt] = *(const short8*)(gG + (size_t)(j + 16)*4096 + off);
                c0[kb][nt] = *(const short8*)(gG + (size_t)j*4096 + off);
            }
    };
    // rt sweep for tap pair {j, j+16}: read rt feeds tap j at mt=rt-1 and
    // tap j+16 at mt=rt.  LDS row = rg*128 + 16*rt + 16 - j + l15.
    auto sweep = [&](const short8 (&c0)[2][2], const short8 (&c1)[2][2], int j) {
        const int swz  = ((l15 - j) & 7) << 4;
        const int rowb = (rg*128 + 16 - j + l15) * 128;
        const int cb0 = (q * 16) ^ swz;
        const int cb1 = (64 + q * 16) ^ swz;
        short8 av[9], bv[9];
#pragma unroll
        for (int rt = 0; rt <= 8; ++rt)
            av[rt] = *(const short8*)(uS + (rowb + rt * 2048 + cb0));
#pragma unroll
        for (int rt = 0; rt <= 8; ++rt)
            bv[rt] = *(const short8*)(uS + (rowb + rt * 2048 + cb1));
#pragma unroll
        for (int rt = 0; rt <= 8; ++rt) {
            if (rt >= 1) {                  // tap j,   mt = rt-1
#pragma unroll
                for (int nt = 0; nt < 2; ++nt)
                    acc[rt-1][nt] = __builtin_amdgcn_mfma_f32_16x16x32_bf16(
                        av[rt], c0[0][nt], acc[rt-1][nt], 0, 0, 0);
            }
            if (rt <= 7) {                  // tap j+16, mt = rt
#pragma unroll
                for (int nt = 0; nt < 2; ++nt)
                    acc[rt][nt] = __builtin_amdgcn_mfma_f32_16x16x32_bf16(
                        av[rt], c1[0][nt], acc[rt][nt], 0, 0, 0);
            }
        }
#pragma unroll
        for (int rt = 0; rt <= 8; ++rt) {
            if (rt >= 1) {
#pragma unroll
                for (int nt = 0; nt < 2; ++nt)
                    acc[rt-1][nt] = __builtin_amdgcn_mfma_f32_16x16x32_bf16(
                        bv[rt], c0[1][nt], acc[rt-1][nt], 0, 0, 0);
            }
            if (rt <= 7) {
#pragma unroll
                for (int nt = 0; nt < 2; ++nt)
                    acc[rt][nt] = __builtin_amdgcn_mfma_f32_16x16x32_bf16(
                        bv[rt], c1[1][nt], acc[rt][nt], 0, 0, 0);
            }
        }
    };

    // software-pipelined main loop: two static G buffer sets, unroll-2 over j
    short8 bA0[2][2], bA1[2][2], bB0[2][2], bB1[2][2];
    loadG2(bA0, bA1, 0);
#pragma unroll 1
    for (int jj = 0; jj < 8; ++jj) {
        loadG2(bB0, bB1, 2*jj + 1);         // prefetch j+1 (hidden under sweep j)
        sweep(bA0, bA1, 2*jj);
        if (jj < 7) loadG2(bA0, bA1, 2*jj + 2);  // prefetch j+2
        sweep(bB0, bB1, 2*jj + 1);
    }

    // tail: tap 32 (LDS row = rg*128 + 16mt + l15)
    {
        short8 bt[2][2];
#pragma unroll
        for (int kb = 0; kb < 2; ++kb)
#pragma unroll
            for (int nt = 0; nt < 2; ++nt)
                bt[kb][nt] = *(const short8*)(gG + (size_t)32*4096
                                  + (size_t)(l15 + 16*(2*nhalf + nt))*64 + kb*32 + q*8);
        const int swz  = (l15 & 7) << 4;
        const int rowb = (rg*128 + l15) * 128;
        const int cb0 = (q * 16) ^ swz;
        const int cb1 = (64 + q * 16) ^ swz;
        short8 av[8], bv[8];
#pragma unroll
        for (int mt = 0; mt < 8; ++mt)
            av[mt] = *(const short8*)(uS + (rowb + mt * 2048 + cb0));
#pragma unroll
        for (int mt = 0; mt < 8; ++mt)
            bv[mt] = *(const short8*)(uS + (rowb + mt * 2048 + cb1));
#pragma unroll
        for (int mt = 0; mt < 8; ++mt)
#pragma unroll
            for (int nt = 0; nt < 2; ++nt)
                acc[mt][nt] = __builtin_amdgcn_mfma_f32_16x16x32_bf16(
                    av[mt], bt[0][nt], acc[mt][nt], 0, 0, 0);
#pragma unroll
        for (int mt = 0; mt < 8; ++mt)
#pragma unroll
            for (int nt = 0; nt < 2; ++nt)
                acc[mt][nt] = __builtin_amdgcn_mfma_f32_16x16x32_bf16(
                    bv[mt], bt[1][nt], acc[mt][nt], 0, 0, 0);
    }

    // epilogue: row = rg*128 + 16mt + q*4 + r, col = 32*nhalf + 16nt + l15
    const bool zblk = (blockIdx.x == 0 && rg == 0);
#pragma unroll
    for (int mt = 0; mt < 8; ++mt)
#pragma unroll
        for (int nt = 0; nt < 2; ++nt) {
            const int p = l15 + 32*nhalf + 16*nt;
#pragma unroll
            for (int r = 0; r < 4; ++r) {
                int tl = rg*128 + mt*16 + q*4 + r;
                float v = acc[mt][nt][r];
                if (zblk && mt < 3) v += gZ[(mt*16 + q*4 + r)*64 + p];  // t < 48
                out[(size_t)(t0 + tl)*64 + p] = v;
            }
        }
}

extern "C" void kernel_launch(void* const* d_in, const int* in_sizes, int n_in,
                              void* d_out, int out_size, void* d_ws, size_t ws_size,
                              hipStream_t stream) {
    const float* u  = (const float*)d_in[0];
    const float* x0 = (const float*)d_in[1];
    const float* A  = (const float*)d_in[2];
    const float* B  = (const float*)d_in[3];
    const float* C  = (const float*)d_in[4];
    const float* D  = (const float*)d_in[5];
    float* out = (float*)d_out;

    unsigned short* gG = (unsigned short*)d_ws;                   // 33*4096 bf16
    float* gZ = (float*)((char*)d_ws + 272384);                   // 48*64 fp32
    unsigned short* uB = (unsigned short*)((char*)d_ws + 284672); // (T+32)*64 bf16

    hipLaunchKernelGGL(k_prep_pow, dim3(ZLEN), dim3(256), 0, stream,
                       A, B, C, D, x0, gG, gZ);
    hipLaunchKernelGGL(k_cast, dim3((UB_ROWS * 64 / 8) / 256), dim3(256),
                       0, stream, u, uB);
    hipLaunchKernelGGL(k_conv, dim3(T_LEN / ROWS), dim3(256), 0, stream,
                       uB, gG, gZ, out);
}